// Round 3
// baseline (45.453 us; speedup 1.0000x reference)
//
#include <hip/hip_runtime.h>

#define NPTS   8192
#define BLOCK  256
#define IPT    2                          // i's per thread (register tile)
#define CHUNKS 128
#define JT     (NPTS / CHUNKS)            // 64 j's per block

__global__ __launch_bounds__(BLOCK) void nbody_force(
    const float* __restrict__ pos, float* __restrict__ out)
{
    const int tid   = threadIdx.x;
    const int ibase = blockIdx.x * (BLOCK * IPT) + tid;
    const int j0    = blockIdx.y * JT;

    float xi[IPT], yi[IPT], zi[IPT];
    float fx[IPT], fy[IPT], fz[IPT];
#pragma unroll
    for (int p = 0; p < IPT; ++p) {
        const int i = ibase + p * BLOCK;
        xi[p] = pos[i * 3 + 0];
        yi[p] = pos[i * 3 + 1];
        zi[p] = pos[i * 3 + 2];
        fx[p] = 0.0f; fy[p] = 0.0f; fz[p] = 0.0f;
    }

    // j position loads are block-uniform -> scalarize to s_load (scalar pipe);
    // all per-j overhead is amortized over IPT pairs of pure VALU work.
#pragma unroll 8
    for (int t = 0; t < JT; ++t) {
        const int j = j0 + t;
        const float xj = pos[j * 3 + 0];
        const float yj = pos[j * 3 + 1];
        const float zj = pos[j * 3 + 2];

#pragma unroll
        for (int p = 0; p < IPT; ++p) {
            const float dx = xi[p] - xj;
            const float dy = yi[p] - yj;
            const float dz = zi[p] - zj;
            // 1e-12 floor: at i==j, ir3 = 1e18 and dx==0 -> exact 0 (no NaN
            // guard needed); error from omitting +1e-5 on dist is << threshold.
            const float r2  = fmaf(dz, dz, fmaf(dy, dy, fmaf(dx, dx, 1e-12f)));
            const float ir  = __builtin_amdgcn_rsqf(r2);
            const float ir3 = ir * ir * ir;
            fx[p] = fmaf(dx, ir3, fx[p]);
            fy[p] = fmaf(dy, ir3, fy[p]);
            fz[p] = fmaf(dz, ir3, fz[p]);
        }
    }

#pragma unroll
    for (int p = 0; p < IPT; ++p) {
        const int i = ibase + p * BLOCK;
        atomicAdd(&out[i * 3 + 0], fx[p]);
        atomicAdd(&out[i * 3 + 1], fy[p]);
        atomicAdd(&out[i * 3 + 2], fz[p]);
    }
}

extern "C" void kernel_launch(void* const* d_in, const int* in_sizes, int n_in,
                              void* d_out, int out_size, void* d_ws, size_t ws_size,
                              hipStream_t stream)
{
    const float* pos = (const float*)d_in[0];
    float* out = (float*)d_out;

    // Output is accumulated via atomics -> must start at zero every call.
    hipMemsetAsync(d_out, 0, (size_t)out_size * sizeof(float), stream);

    dim3 grid(NPTS / (BLOCK * IPT), CHUNKS);   // 16 x 128 = 2048 blocks
    dim3 block(BLOCK);
    nbody_force<<<grid, block, 0, stream>>>(pos, out);
}

// Round 4
// 32.078 us; speedup vs baseline: 1.4169x; 1.4169x over previous
//
#include <hip/hip_runtime.h>

#define NPTS   8192
#define BLOCK  256
#define CHUNKS 64
#define JT     (NPTS / CHUNKS)   // 128 j's per block-chunk

// Phase 1: block (bx, by) computes, for its 256 i's, the partial force over
// j in [by*JT, (by+1)*JT), and stores to ws[by] with plain coalesced stores.
// No atomics anywhere -> no write-through RMW traffic (R2's 36.8 MB killer).
__global__ __launch_bounds__(BLOCK) void nbody_partial(
    const float* __restrict__ pos, float* __restrict__ ws)
{
    const int tid = threadIdx.x;
    const int i   = blockIdx.x * BLOCK + tid;
    const int j0  = blockIdx.y * JT;

    const float xi = pos[i * 3 + 0];
    const float yi = pos[i * 3 + 1];
    const float zi = pos[i * 3 + 2];

    float fx = 0.0f, fy = 0.0f, fz = 0.0f;

    const float4* __restrict__ pos4 = (const float4*)pos;

#define PAIR(px, py, pz)                                                    \
    {                                                                       \
        const float dx = xi - (px);                                         \
        const float dy = yi - (py);                                         \
        const float dz = zi - (pz);                                         \
        const float r2  = fmaf(dz, dz, fmaf(dy, dy, fmaf(dx, dx, 1e-12f))); \
        const float ir  = __builtin_amdgcn_rsqf(r2);                        \
        const float ir3 = ir * ir * ir;                                     \
        fx = fmaf(dx, ir3, fx);                                             \
        fy = fmaf(dy, ir3, fy);                                             \
        fz = fmaf(dz, ir3, fz);                                             \
    }

    // 4 points per 3 float4 loads (block-uniform addresses, L1/L2-broadcast).
#pragma unroll 4
    for (int g = 0; g < JT / 4; ++g) {
        const int base = (j0 / 4 + g) * 3;       // float4 index
        const float4 a = pos4[base + 0];
        const float4 b = pos4[base + 1];
        const float4 c = pos4[base + 2];
        PAIR(a.x, a.y, a.z);
        PAIR(a.w, b.x, b.y);
        PAIR(b.z, b.w, c.x);
        PAIR(c.y, c.z, c.w);
    }
#undef PAIR

    float* o = ws + ((size_t)blockIdx.y * NPTS + i) * 3;
    o[0] = fx; o[1] = fy; o[2] = fz;
}

// Phase 2: out[e] = sum over chunks of ws[ch][e]. Fully coalesced.
__global__ __launch_bounds__(BLOCK) void nbody_reduce(
    const float* __restrict__ ws, float* __restrict__ out)
{
    const int e = blockIdx.x * BLOCK + threadIdx.x;   // 0 .. NPTS*3-1
    float s = 0.0f;
#pragma unroll 16
    for (int ch = 0; ch < CHUNKS; ++ch)
        s += ws[(size_t)ch * NPTS * 3 + e];
    out[e] = s;
}

extern "C" void kernel_launch(void* const* d_in, const int* in_sizes, int n_in,
                              void* d_out, int out_size, void* d_ws, size_t ws_size,
                              hipStream_t stream)
{
    const float* pos = (const float*)d_in[0];
    float* out = (float*)d_out;
    float* ws  = (float*)d_ws;    // needs CHUNKS * NPTS * 3 * 4 B = 6.3 MB

    dim3 grid1(NPTS / BLOCK, CHUNKS);   // 32 x 64 = 2048 blocks, 8/CU
    nbody_partial<<<grid1, dim3(BLOCK), 0, stream>>>(pos, ws);

    dim3 grid2(NPTS * 3 / BLOCK);       // 96 blocks
    nbody_reduce<<<grid2, dim3(BLOCK), 0, stream>>>(ws, out);
}